// Round 4
// baseline (1885.743 us; speedup 1.0000x reference)
//
#include <hip/hip_runtime.h>
#include <stdint.h>

// PillarFeatureNet on MI355X.
// B=2, T=5, GX=GY=512, C=64, N=600000 points (6 f32 each: b,x,y,z,inten,t)
// Output: (B, C, T, GY, GX) float32 = 167,772,160 elements (671 MB).
//
// Voxelization matches the oracle's canonicalized form: (x - pcr) * (1/vox)
// in f32 with exact reciprocal 5.0f, ops pinned with __fadd_rn/__fmul_rn so
// the compiler cannot contract (x+51.2f)*5.0f into fmaf(x,5,256) (different
// rounding). This is the membership-critical path: divide-vs-multiply differ
// for quotients within ~1.5e-8*cf below an integer, where RN32(v*5) rounds UP
// to the integer but a correctly-rounded divide (and f64) stay below.
//
// ws layout (~43 MB): counts u32[NSEG] @0 | sums f32[NSEG*3] @10,485,760 |
// nvalid u32 @41,943,040 | px f64[SB*64] @41,943,296 | px2 f64[SB*64] |
// scale f32[64] | shift f32[64]

#define GXc 512
#define GYc 512
#define Bc  2
#define Tc  5
#define Cc  64
#define NSEG (Bc * Tc * GYc * GXc)   // 2,621,440
#define SB  1024                     // stats partial blocks

// Per-point preamble: voxel coords, validity, segment id.
// f32 throughout, multiply by exact reciprocal 5.0f, IEEE-pinned.
__device__ __forceinline__ bool point_prep(const float* __restrict__ p,
    float& x, float& y, float& z, float& inten,
    int& bid, int& tid, int& cx, int& cy, int& seg)
{
    float b0 = p[0];
    x = p[1]; y = p[2]; z = p[3]; inten = p[4];
    float tf = p[5];
    float cf0 = __fmul_rn(__fadd_rn(x, 51.2f), 5.0f);   // (x - (-51.2)) * (1/0.2)
    float cf1 = __fmul_rn(__fadd_rn(y, 51.2f), 5.0f);
    bool valid = (cf0 >= 0.0f) && (cf0 < 512.0f) && (cf1 >= 0.0f) && (cf1 < 512.0f);
    int icx = (int)cf0; icx = icx < 0 ? 0 : (icx > GXc - 1 ? GXc - 1 : icx);
    int icy = (int)cf1; icy = icy < 0 ? 0 : (icy > GYc - 1 ? GYc - 1 : icy);
    cx = icx; cy = icy;
    bid = (int)b0;
    tid = (int)tf;
    seg = ((bid * Tc + tid) * GYc + cy) * GXc + cx;
    return valid;
}

// The 9 features and the channel-c output of feats @ W (f32).
__device__ __forceinline__ float point_x(
    float x, float y, float z, float inten, int cx, int cy, int seg,
    const uint32_t* __restrict__ counts, const float* __restrict__ sums,
    const float* __restrict__ W, int c)
{
    float cnt = (float)counts[seg];          // >= 1 for valid points
    float m0 = sums[seg * 3 + 0] / cnt;
    float m1 = sums[seg * 3 + 1] / cnt;
    float m2 = sums[seg * 3 + 2] / cnt;
    // center = cx*vox + vox*0.5 + pcr, pinned f32 order
    float ctr0 = __fadd_rn(__fadd_rn(__fmul_rn((float)cx, 0.2f), 0.1f), -51.2f);
    float ctr1 = __fadd_rn(__fadd_rn(__fmul_rn((float)cy, 0.2f), 0.1f), -51.2f);
    float f0 = x, f1 = y, f2 = z, f3 = inten;
    float f4 = x - m0, f5 = y - m1, f6 = z - m2;
    float f7 = x - ctr0, f8 = y - ctr1;
    float xc;
    xc = f0 * W[0 * Cc + c];
    xc = fmaf(f1, W[1 * Cc + c], xc);
    xc = fmaf(f2, W[2 * Cc + c], xc);
    xc = fmaf(f3, W[3 * Cc + c], xc);
    xc = fmaf(f4, W[4 * Cc + c], xc);
    xc = fmaf(f5, W[5 * Cc + c], xc);
    xc = fmaf(f6, W[6 * Cc + c], xc);
    xc = fmaf(f7, W[7 * Cc + c], xc);
    xc = fmaf(f8, W[8 * Cc + c], xc);
    return xc;
}

extern "C" __global__ __launch_bounds__(256)
void k_count(const float* __restrict__ pts, uint32_t* __restrict__ counts,
             float* __restrict__ sums, uint32_t* __restrict__ nvalid, int n)
{
    int i = blockIdx.x * 256 + threadIdx.x;
    if (i >= n) return;
    float x, y, z, it; int bid, tid, cx, cy, seg;
    bool v = point_prep(pts + (size_t)i * 6, x, y, z, it, bid, tid, cx, cy, seg);
    if (!v) return;
    atomicAdd(&counts[seg], 1u);
    atomicAdd(&sums[seg * 3 + 0], x);
    atomicAdd(&sums[seg * 3 + 1], y);
    atomicAdd(&sums[seg * 3 + 2], z);
    atomicAdd(nvalid, 1u);
}

// Wave-per-point: lane c computes channel c. Double partials per block.
extern "C" __global__ __launch_bounds__(256)
void k_stats(const float* __restrict__ pts, const uint32_t* __restrict__ counts,
             const float* __restrict__ sums, const float* __restrict__ W,
             double* __restrict__ px, double* __restrict__ px2, int n)
{
    int c = threadIdx.x & 63;
    int sub = threadIdx.x >> 6;   // 4 points per block
    double ax = 0.0, ax2 = 0.0;
    for (int i = blockIdx.x * 4 + sub; i < n; i += (int)gridDim.x * 4) {
        float x, y, z, it; int bid, tid, cx, cy, seg;
        bool v = point_prep(pts + (size_t)i * 6, x, y, z, it, bid, tid, cx, cy, seg);
        if (!v) continue;
        float xc = point_x(x, y, z, it, cx, cy, seg, counts, sums, W, c);
        ax  += (double)xc;
        ax2 += (double)xc * (double)xc;
    }
    __shared__ double sred[256];
    sred[threadIdx.x] = ax;
    __syncthreads();
    if (sub == 0)
        px[(size_t)blockIdx.x * 64 + c] = sred[c] + sred[c + 64] + sred[c + 128] + sred[c + 192];
    __syncthreads();
    sred[threadIdx.x] = ax2;
    __syncthreads();
    if (sub == 0)
        px2[(size_t)blockIdx.x * 64 + c] = sred[c] + sred[c + 64] + sred[c + 128] + sred[c + 192];
}

extern "C" __global__ __launch_bounds__(64)
void k_finalize(const double* __restrict__ px, const double* __restrict__ px2,
                const uint32_t* __restrict__ nvalid,
                const float* __restrict__ gamma, const float* __restrict__ beta,
                float* __restrict__ scale, float* __restrict__ shift)
{
    int c = threadIdx.x;
    double sx = 0.0, sx2 = 0.0;
    for (int b = 0; b < SB; b++) {
        sx  += px[(size_t)b * 64 + c];
        sx2 += px2[(size_t)b * 64 + c];
    }
    uint32_t nvu = *nvalid; if (nvu < 1u) nvu = 1u;
    double nv = (double)nvu;
    double mu = sx / nv;
    double var = sx2 / nv - mu * mu;
    float r = (float)(1.0 / sqrt(var + 0.001));
    float sc = gamma[c] * r;
    scale[c] = sc;
    shift[c] = fmaf(-(float)mu, sc, beta[c]);
}

// Scatter: y = relu(x*scale+shift); atomicMax into transposed canvas.
// Post-ReLU values are >= 0, so float-max == uint-max on bit patterns with
// memset-0 identity. Skip y<=0 (identity).
extern "C" __global__ __launch_bounds__(256)
void k_scatter(const float* __restrict__ pts, const uint32_t* __restrict__ counts,
               const float* __restrict__ sums, const float* __restrict__ W,
               const float* __restrict__ scale, const float* __restrict__ shift,
               unsigned int* __restrict__ out, int n)
{
    int c = threadIdx.x & 63;
    int sub = threadIdx.x >> 6;
    int i = blockIdx.x * 4 + sub;
    if (i >= n) return;
    float x, y, z, it; int bid, tid, cx, cy, seg;
    bool v = point_prep(pts + (size_t)i * 6, x, y, z, it, bid, tid, cx, cy, seg);
    if (!v) return;
    float xc = point_x(x, y, z, it, cx, cy, seg, counts, sums, W, c);
    float yv = fmaf(xc, scale[c], shift[c]);
    if (yv > 0.0f) {
        size_t oidx = ((((size_t)bid * Cc + c) * Tc + tid) * ((size_t)GYc * GXc))
                    + (size_t)cy * GXc + cx;
        atomicMax(&out[oidx], __float_as_uint(yv));
    }
}

extern "C" void kernel_launch(void* const* d_in, const int* in_sizes, int n_in,
                              void* d_out, int out_size, void* d_ws, size_t ws_size,
                              hipStream_t stream)
{
    const float* pts   = (const float*)d_in[0];
    const float* W     = (const float*)d_in[1];
    const float* gamma = (const float*)d_in[2];
    const float* beta  = (const float*)d_in[3];
    int n = in_sizes[0] / 6;

    uint8_t* ws = (uint8_t*)d_ws;
    const size_t OFF_SUMS   = (size_t)NSEG * 4;                 // 10,485,760
    const size_t OFF_NVALID = OFF_SUMS + (size_t)NSEG * 3 * 4;  // 41,943,040
    const size_t OFF_PX     = OFF_NVALID + 256;                 // 41,943,296
    const size_t OFF_PX2    = OFF_PX + (size_t)SB * 64 * 8;
    const size_t OFF_SCALE  = OFF_PX2 + (size_t)SB * 64 * 8;
    const size_t OFF_SHIFT  = OFF_SCALE + 256;

    uint32_t* counts = (uint32_t*)ws;
    float*    sums   = (float*)(ws + OFF_SUMS);
    uint32_t* nvalid = (uint32_t*)(ws + OFF_NVALID);
    double*   px     = (double*)(ws + OFF_PX);
    double*   px2    = (double*)(ws + OFF_PX2);
    float*    scale  = (float*)(ws + OFF_SCALE);
    float*    shift  = (float*)(ws + OFF_SHIFT);

    // Zero the canvas (identity for uint-max) and the accumulators.
    hipMemsetAsync(d_out, 0, (size_t)out_size * sizeof(float), stream);
    hipMemsetAsync(ws, 0, OFF_PX, stream);

    k_count   <<<(n + 255) / 256, 256, 0, stream>>>(pts, counts, sums, nvalid, n);
    k_stats   <<<SB, 256, 0, stream>>>(pts, counts, sums, W, px, px2, n);
    k_finalize<<<1, 64, 0, stream>>>(px, px2, nvalid, gamma, beta, scale, shift);
    k_scatter <<<(n + 3) / 4, 256, 0, stream>>>(pts, counts, sums, W, scale, shift,
                                                (unsigned int*)d_out, n);
}